// Round 12
// baseline (734.973 us; speedup 1.0000x reference)
//
#include <hip/hip_runtime.h>
#include <math.h>

// B=32, C_IN=3, H=W=128, MID=64
// All three 3x3 convs on matrix cores via fp16 2-way split (hi + lo*2^11):
// 3 MFMA products per tile => ~fp32 precision. 9 shifted K=64 GEMMs per conv,
// input staged in LDS as split-fp16, pos stride 144 B = [32ci hi|32ci lo|pad16]
// (144 keeps half8 reads 16B-aligned; 140 "bank fix" regressed 34% — r8).
// r9: fences in wide kernels cost ~78us — instead this round fuses BN-stats
// into conv epilogues (pool values written exactly once; per-block LDS
// accumulate + one global atomicAdd/ch) and inlines bn0/finalize into
// consumers. Kernel-boundary ordering only; launches 15 -> 8.

typedef _Float16 half8_t __attribute__((ext_vector_type(8)));
typedef __fp16 fp16x2 __attribute__((ext_vector_type(2)));
typedef float f32x4 __attribute__((ext_vector_type(4)));

// ------- prep: zero stats + W[co][ci][kh][kw] -> A-frag order, fp16 split -------
// Wp fp16 idx = (((s*2+p)*8 + (ci>>3))*64 + co)*8 + (ci&7); p=0 hi, p=1 lo*2^11
__global__ __launch_bounds__(256) void k_prep(const float* __restrict__ w1,
                                              const float* __restrict__ w2,
                                              const float* __restrict__ w3,
                                              _Float16* __restrict__ Wp,
                                              float* __restrict__ zb) {
  int blk = blockIdx.x;
  if (blk >= 432) {           // zero st(384) + xst(16)
    int i = (blk - 432) * 256 + threadIdx.x;
    if (i < 400) zb[i] = 0.f;
    return;
  }
  int layer = blk / 144;
  const float* w = (layer == 0) ? w1 : (layer == 1) ? w2 : w3;
  _Float16* W = Wp + (size_t)layer * 73728;
  int i = (blk % 144) * 256 + threadIdx.x;   // 0..36863
  int s = i >> 12, rem = i & 4095;
  int ci = rem >> 6, co = rem & 63;
  float wv = w[(co * 64 + ci) * 9 + s];
  _Float16 hi = (_Float16)wv;
  _Float16 lo = (_Float16)((wv - (float)hi) * 2048.0f);
  int g = ci >> 3, e = ci & 7;
  W[(((size_t)(s * 2 + 0) * 8 + g) * 64 + co) * 8 + e] = hi;
  W[(((size_t)(s * 2 + 1) * 8 + g) * 64 + co) * 8 + e] = lo;
}

// ---------------- x channel stats (for analytic BN0) ----------------
__global__ __launch_bounds__(256) void k_xstats(const float* __restrict__ x,
                                                float* __restrict__ xst) {
  int g0 = blockIdx.x * 256 + threadIdx.x;
  float a[9] = {0,0,0,0,0,0,0,0,0};
  for (int g = g0; g < 524288; g += 1024 * 256) {
    int b = g >> 14, p = g & 16383;
    const float* xb = x + (size_t)b * 49152 + p;
    float x0 = xb[0], x1 = xb[16384], x2 = xb[32768];
    a[0] += x0; a[1] += x1; a[2] += x2;
    a[3] += x0 * x0; a[4] += x0 * x1; a[5] += x0 * x2;
    a[6] += x1 * x1; a[7] += x1 * x2; a[8] += x2 * x2;
  }
  __shared__ float red[256];
  for (int k = 0; k < 9; ++k) {
    red[threadIdx.x] = a[k];
    __syncthreads();
    for (int s = 128; s > 0; s >>= 1) {
      if (threadIdx.x < s) red[threadIdx.x] += red[threadIdx.x + s];
      __syncthreads();
    }
    if (threadIdx.x == 0) atomicAdd(&xst[k], red[0]);
    __syncthreads();
  }
}

// ------- layer1 on MFMA: bnrelu(w0.x) staged split-fp16 -> 9-shift GEMM -> pool
// BN0 computed inline per block from xst (analytic). Pool epilogue also
// accumulates h1 per-channel sum/sumsq into st (layer-1 slots).
__global__ __launch_bounds__(256) void k_conv1_mfma(
    const float* __restrict__ x, const float* __restrict__ w0,
    const _Float16* __restrict__ Wp, const float* __restrict__ xst,
    const float* __restrict__ gamma, const float* __restrict__ beta,
    float* __restrict__ out, float* __restrict__ st) {
  __shared__ __align__(16) unsigned char smem[51488];
  __shared__ float ssum[64], ssq[64];
  float* x_lds = (float*)(smem + 47520);

  int bid = blockIdx.x;
  int cb = bid & 1, pr = (bid >> 1) % 62, b = (bid >> 1) / 62;
  int CB = cb * 62;
  int t = threadIdx.x;
  int lane = t & 63, wv = t >> 6;
  int cwv = wv * 16;
  int l15 = lane & 15, l4 = lane >> 4;

  for (int i = t; i < 990; i += 256) {
    int ch = i / 330, pos = i - ch * 330;
    int ir = pos / 66, ic = pos - ir * 66;
    x_lds[ch * 330 + pos] =
        x[((size_t)(b * 3 + ch) << 14) + (2 * pr + ir) * 128 + CB + ic];
  }

  const float invN0 = 1.f / 524288.f;
  float mu0 = xst[0]*invN0, mu1 = xst[1]*invN0, mu2 = xst[2]*invN0;
  float M00 = xst[3]*invN0, M01 = xst[4]*invN0, M02 = xst[5]*invN0;
  float M11 = xst[6]*invN0, M12 = xst[7]*invN0, M22 = xst[8]*invN0;

  f32x4 acc1[3][4], acc2[3][4];
  #pragma unroll
  for (int r = 0; r < 3; ++r)
    #pragma unroll
    for (int ct = 0; ct < 4; ++ct) {
      acc1[r][ct] = (f32x4)0.f;
      acc2[r][ct] = (f32x4)0.f;
    }

  int pair = t & 15;
  int posb = t >> 4;
  int LB = l15 * 144 + l4 * 16;

  for (int q = 0; q < 2; ++q) {
    int ci0 = q * 32 + 2 * pair, ci1 = ci0 + 1;
    float w00 = w0[ci0*3], w01 = w0[ci0*3+1], w02 = w0[ci0*3+2];
    float w10 = w0[ci1*3], w11 = w0[ci1*3+1], w12 = w0[ci1*3+2];
    // inline analytic BN0 (was k_bn0)
    float m0 = w00*mu0 + w01*mu1 + w02*mu2;
    float e20 = w00*w00*M00 + w01*w01*M11 + w02*w02*M22
              + 2.f*(w00*w01*M01 + w00*w02*M02 + w01*w02*M12);
    float sc0 = gamma[ci0] / sqrtf(e20 - m0*m0 + 1e-5f);
    float bi0 = beta[ci0] - m0*sc0;
    float m1 = w10*mu0 + w11*mu1 + w12*mu2;
    float e21 = w10*w10*M00 + w11*w11*M11 + w12*w12*M22
              + 2.f*(w10*w11*M01 + w10*w12*M02 + w11*w12*M12);
    float sc1 = gamma[ci1] / sqrtf(e21 - m1*m1 + 1e-5f);
    float bi1 = beta[ci1] - m1*sc1;
    __syncthreads();
    for (int pos = posb; pos < 330; pos += 16) {
      float x0 = x_lds[pos], x1 = x_lds[330 + pos], x2 = x_lds[660 + pos];
      float v0 = fmaxf(fmaf(fmaf(x2, w02, fmaf(x1, w01, x0 * w00)), sc0, bi0), 0.f);
      float v1 = fmaxf(fmaf(fmaf(x2, w12, fmaf(x1, w11, x0 * w10)), sc1, bi1), 0.f);
      fp16x2 hv = __builtin_amdgcn_cvt_pkrtz(v0, v1);
      float l0 = (v0 - (float)hv[0]) * 2048.f;
      float l1 = (v1 - (float)hv[1]) * 2048.f;
      fp16x2 lv = __builtin_amdgcn_cvt_pkrtz(l0, l1);
      int base = pos * 144 + pair * 4;
      *(fp16x2*)(smem + base) = hv;
      *(fp16x2*)(smem + base + 64) = lv;
    }
    __syncthreads();

    #pragma unroll
    for (int s = 0; s < 9; ++s) {
      const int kh = s / 3, kw = s % 3;
      half8_t Ah[4], Al[4];
      #pragma unroll
      for (int ct = 0; ct < 4; ++ct) {
        Ah[ct] = *(const half8_t*)(Wp + ((size_t)((s*2+0)*8 + q*4 + l4) * 64 + ct*16 + l15) * 8);
        Al[ct] = *(const half8_t*)(Wp + ((size_t)((s*2+1)*8 + q*4 + l4) * 64 + ct*16 + l15) * 8);
      }
      #pragma unroll
      for (int r = 0; r < 3; ++r) {
        int rowoff = ((r + kh) * 66 + cwv + kw) * 144 + LB;
        half8_t Bh = *(const half8_t*)(smem + rowoff);
        half8_t Bl = *(const half8_t*)(smem + rowoff + 64);
        #pragma unroll
        for (int ct = 0; ct < 4; ++ct) {
          acc1[r][ct] = __builtin_amdgcn_mfma_f32_16x16x32_f16(Ah[ct], Bh, acc1[r][ct], 0, 0, 0);
          acc2[r][ct] = __builtin_amdgcn_mfma_f32_16x16x32_f16(Ah[ct], Bl, acc2[r][ct], 0, 0, 0);
          acc2[r][ct] = __builtin_amdgcn_mfma_f32_16x16x32_f16(Al[ct], Bh, acc2[r][ct], 0, 0, 0);
        }
      }
    }
  }

  __syncthreads();
  float* ctile = (float*)smem;   // [64 co][3 r][65]
  #pragma unroll
  for (int r = 0; r < 3; ++r)
    #pragma unroll
    for (int ct = 0; ct < 4; ++ct)
      #pragma unroll
      for (int e = 0; e < 4; ++e) {
        int co = ct * 16 + l4 * 4 + e;
        ctile[(co * 3 + r) * 65 + cwv + l15] =
            acc1[r][ct][e] + acc2[r][ct][e] * (1.f / 2048.f);
      }
  if (t < 64) { ssum[t] = 0.f; ssq[t] = 0.f; }
  __syncthreads();
  for (int i = t; i < 64 * 31; i += 256) {
    int co = i / 31, pcl = i - co * 31;
    float m = -INFINITY;
    #pragma unroll
    for (int dr = 0; dr < 3; ++dr)
      #pragma unroll
      for (int dc = 0; dc < 3; ++dc)
        m = fmaxf(m, ctile[(co * 3 + dr) * 65 + 2 * pcl + dc]);
    atomicAdd(&ssum[co], m);
    atomicAdd(&ssq[co], m * m);
    out[((size_t)(b * 64 + co) * 62 + pr) * 62 + cb * 31 + pcl] = m;
  }
  __syncthreads();
  if (t < 64) {
    atomicAdd(&st[2 * t],     ssum[t]);
    atomicAdd(&st[2 * t + 1], ssq[t]);
  }
}

// ------- layers 2/3 on MFMA: bnrelu(in) staged split-fp16 -> 9-shift GEMM -> pool
// BN params computed in-block from st_in (was k_finalize); epilogue fuses
// output stats into st_out (was k_stats).
template<int IN, int POOLW, int NH>
__global__ __launch_bounds__(256) void k_convpool_mfma(
    const float* __restrict__ in, const _Float16* __restrict__ Wp,
    const float* __restrict__ st_in, const float* __restrict__ gamma,
    const float* __restrict__ beta, int layer, float invN,
    float* __restrict__ out, float* __restrict__ st_out) {
  __shared__ __align__(16) unsigned char smem[25344];  // stage 24480 / ctile 25344
  __shared__ float sbl[128];
  __shared__ float ssum[64], ssq[64];

  int bid = blockIdx.x;
  int h  = (NH == 2) ? (bid & 1) : 0;
  int pw = (NH == 2) ? (bid >> 1) : bid;
  int pr = pw % POOLW;
  int b  = pw / POOLW;
  int CB = h * 30;
  int t = threadIdx.x;
  int lane = t & 63, wv = t >> 6;
  int l15 = lane & 15, l4 = lane >> 4;
  int wc = wv & 1, wo = wv >> 1;

  if (t < 64) {   // inline finalize (covered by q=0's leading barrier)
    float m = st_in[2 * t] * invN;
    float var = st_in[2 * t + 1] * invN - m * m;
    float sc = gamma[layer * 64 + t] / sqrtf(var + 1e-5f);
    sbl[2 * t] = sc;
    sbl[2 * t + 1] = beta[layer * 64 + t] - m * sc;
  }

  f32x4 acc1[3][2], acc2[3][2];
  #pragma unroll
  for (int r = 0; r < 3; ++r)
    #pragma unroll
    for (int c = 0; c < 2; ++c) { acc1[r][c] = (f32x4)0.f; acc2[r][c] = (f32x4)0.f; }

  for (int q = 0; q < 2; ++q) {
    __syncthreads();
    for (int li = t; li < 5440; li += 256) {
      int ci = li / 170, pos = li - ci * 170;
      int ir = pos / 34, ic = pos - ir * 34;
      int gci = q * 32 + ci;
      int gc = CB + ic;
      float v = 0.f;
      if (gc < IN)
        v = fmaxf(fmaf(in[((size_t)(b * 64 + gci) * IN + 2 * pr + ir) * IN + gc],
                       sbl[2 * gci], sbl[2 * gci + 1]), 0.f);
      _Float16 hi = (_Float16)v;
      _Float16 lo = (_Float16)((v - (float)hi) * 2048.f);
      int base = pos * 144 + ci * 2;
      *(_Float16*)(smem + base) = hi;
      *(_Float16*)(smem + base + 64) = lo;
    }
    __syncthreads();
    #pragma unroll
    for (int s = 0; s < 9; ++s) {
      const int kh = s / 3, kw = s % 3;
      half8_t Ah[2], Al[2];
      #pragma unroll
      for (int cti = 0; cti < 2; ++cti) {
        int co = (wo * 2 + cti) * 16 + l15;
        Ah[cti] = *(const half8_t*)(Wp + ((size_t)((s*2+0)*8 + q*4 + l4) * 64 + co) * 8);
        Al[cti] = *(const half8_t*)(Wp + ((size_t)((s*2+1)*8 + q*4 + l4) * 64 + co) * 8);
      }
      #pragma unroll
      for (int r = 0; r < 3; ++r) {
        int rowoff = ((r + kh) * 34 + wc * 16 + l15 + kw) * 144 + l4 * 16;
        half8_t Bh = *(const half8_t*)(smem + rowoff);
        half8_t Bl = *(const half8_t*)(smem + rowoff + 64);
        #pragma unroll
        for (int cti = 0; cti < 2; ++cti) {
          acc1[r][cti] = __builtin_amdgcn_mfma_f32_16x16x32_f16(Ah[cti], Bh, acc1[r][cti], 0, 0, 0);
          acc2[r][cti] = __builtin_amdgcn_mfma_f32_16x16x32_f16(Ah[cti], Bl, acc2[r][cti], 0, 0, 0);
          acc2[r][cti] = __builtin_amdgcn_mfma_f32_16x16x32_f16(Al[cti], Bh, acc2[r][cti], 0, 0, 0);
        }
      }
    }
  }

  __syncthreads();
  float* ctile = (float*)smem;   // [64 co][3 r][33]
  #pragma unroll
  for (int r = 0; r < 3; ++r)
    #pragma unroll
    for (int cti = 0; cti < 2; ++cti)
      #pragma unroll
      for (int e = 0; e < 4; ++e) {
        int co = (wo * 2 + cti) * 16 + l4 * 4 + e;
        ctile[(co * 3 + r) * 33 + wc * 16 + l15] =
            acc1[r][cti][e] + acc2[r][cti][e] * (1.f / 2048.f);
      }
  if (t < 64) { ssum[t] = 0.f; ssq[t] = 0.f; }
  __syncthreads();
  constexpr int NPC = (NH == 1) ? POOLW : 15;
  int pc0 = h * 15;
  for (int i = t; i < 64 * NPC; i += 256) {
    int co = i / NPC, pcl = i - co * NPC;
    int pc = pc0 + pcl;
    if (pc >= POOLW) continue;
    float m = -INFINITY;
    #pragma unroll
    for (int dr = 0; dr < 3; ++dr)
      #pragma unroll
      for (int dc = 0; dc < 3; ++dc)
        m = fmaxf(m, ctile[(co * 3 + dr) * 33 + 2 * pcl + dc]);
    atomicAdd(&ssum[co], m);
    atomicAdd(&ssq[co], m * m);
    out[((size_t)(b * 64 + co) * POOLW + pr) * POOLW + pc] = m;
  }
  __syncthreads();
  if (t < 64) {
    atomicAdd(&st_out[2 * t],     ssum[t]);
    atomicAdd(&st_out[2 * t + 1], ssq[t]);
  }
}

// ---------------- theta = bnrelu(h3_flat) @ W_reg.T + b_reg ----------------
__global__ __launch_bounds__(256) void k_theta(const float* __restrict__ h3,
                                               const float* __restrict__ st3,
                                               const float* __restrict__ gamma,
                                               const float* __restrict__ beta,
                                               const float* __restrict__ Wreg,
                                               const float* __restrict__ breg,
                                               float* __restrict__ theta_raw) {
  int b = blockIdx.x, tid = threadIdx.x;
  __shared__ float sb3[128];
  if (tid < 64) {   // inline finalize, layer 3
    const float invN = 1.f / 5408.f;
    float m = st3[2 * tid] * invN;
    float var = st3[2 * tid + 1] * invN - m * m;
    float sc = gamma[192 + tid] / sqrtf(var + 1e-5f);
    sb3[2 * tid] = sc;
    sb3[2 * tid + 1] = beta[192 + tid] - m * sc;
  }
  __syncthreads();
  float acc[6] = {0.f, 0.f, 0.f, 0.f, 0.f, 0.f};
  const float* hb = h3 + (size_t)b * 10816;
  for (int i = tid; i < 10816; i += 256) {
    int c = i / 169;
    float f = fmaxf(fmaf(hb[i], sb3[2 * c], sb3[2 * c + 1]), 0.f);
    #pragma unroll
    for (int j = 0; j < 6; ++j) acc[j] += f * Wreg[j * 10816 + i];
  }
  __shared__ float red[6][256];
  #pragma unroll
  for (int j = 0; j < 6; ++j) red[j][tid] = acc[j];
  __syncthreads();
  for (int s = 128; s > 0; s >>= 1) {
    if (tid < s) {
      #pragma unroll
      for (int j = 0; j < 6; ++j) red[j][tid] += red[j][tid + s];
    }
    __syncthreads();
  }
  if (tid < 6) theta_raw[b * 6 + tid] = red[tid][0] + breg[tid];
}

// ---------------- sequential spectral normalization scan ----------------
__global__ void k_spectral(const float* __restrict__ theta_raw,
                           const float* __restrict__ u0v,
                           const float* __restrict__ v0v,
                           float* __restrict__ theta) {
  if (threadIdx.x != 0 || blockIdx.x != 0) return;
  float ua = u0v[0], ub = u0v[1];
  float va = v0v[0], vb = v0v[1], vc = v0v[2];
  for (int n = 0; n < 32; ++n) {
    float W[6];
    #pragma unroll
    for (int k = 0; k < 6; ++k) W[k] = theta_raw[n * 6 + k];
    #pragma unroll
    for (int it = 0; it < 4; ++it) {
      float t0 = W[0]*ua + W[3]*ub;
      float t1 = W[1]*ua + W[4]*ub;
      float t2 = W[2]*ua + W[5]*ub;
      float nv = fmaxf(sqrtf(t0*t0 + t1*t1 + t2*t2), 1e-12f);
      va = t0/nv; vb = t1/nv; vc = t2/nv;
      float s0 = W[0]*va + W[1]*vb + W[2]*vc;
      float s1 = W[3]*va + W[4]*vb + W[5]*vc;
      float nu = fmaxf(sqrtf(s0*s0 + s1*s1), 1e-12f);
      ua = s0/nu; ub = s1/nu;
    }
    float s0 = W[0]*va + W[1]*vb + W[2]*vc;
    float s1 = W[3]*va + W[4]*vb + W[5]*vc;
    float sigma = ua*s0 + ub*s1;
    #pragma unroll
    for (int k = 0; k < 6; ++k) theta[n * 6 + k] = W[k] / sigma;
  }
}

// ---------------- affine grid + reflection bilinear sample ----------------
__global__ __launch_bounds__(256) void k_sample(const float* __restrict__ x,
                                                const float* __restrict__ theta,
                                                float* __restrict__ out) {
  int idx = blockIdx.x * 256 + threadIdx.x;
  int b = idx >> 14, p = idx & 16383;
  int hh = p >> 7, ww = p & 127;
  const float* th = theta + b * 6;
  float xs = (2*ww + 1) * (1.f/128.f) - 1.f;
  float ys = (2*hh + 1) * (1.f/128.f) - 1.f;
  float gx = th[0]*xs + th[1]*ys + th[2];
  float gy = th[3]*xs + th[4]*ys + th[5];
  float ix = ((gx + 1.f) * 128.f - 1.f) * 0.5f;
  float iy = ((gy + 1.f) * 128.f - 1.f) * 0.5f;

  float r;
  r  = fmodf(fabsf(ix + 0.5f), 256.f);
  ix = ((r > 128.f) ? 256.f - r : r) - 0.5f;
  ix = fminf(fmaxf(ix, 0.f), 127.f);
  r  = fmodf(fabsf(iy + 0.5f), 256.f);
  iy = ((r > 128.f) ? 256.f - r : r) - 0.5f;
  iy = fminf(fmaxf(iy, 0.f), 127.f);

  float x0f = floorf(ix), y0f = floorf(iy);
  float wx = ix - x0f, wy = iy - y0f;
  int x0 = (int)x0f; x0 = min(max(x0, 0), 127); int x1 = min(x0 + 1, 127);
  int y0 = (int)y0f; y0 = min(max(y0, 0), 127); int y1 = min(y0 + 1, 127);
  float w00 = (1.f-wx)*(1.f-wy), w10 = wx*(1.f-wy);
  float w01 = (1.f-wx)*wy,       w11 = wx*wy;

  #pragma unroll
  for (int ch = 0; ch < 3; ++ch) {
    const float* xb = x + ((size_t)(b*3 + ch)) * 16384;
    float v = xb[y0*128 + x0]*w00 + xb[y0*128 + x1]*w10
            + xb[y1*128 + x0]*w01 + xb[y1*128 + x1]*w11;
    out[((size_t)(b*3 + ch)) * 16384 + p] = v;
  }
}

extern "C" void kernel_launch(void* const* d_in, const int* in_sizes, int n_in,
                              void* d_out, int out_size, void* d_ws, size_t ws_size,
                              hipStream_t stream) {
  const float* x     = (const float*)d_in[0];
  const float* w0    = (const float*)d_in[1];
  const float* w1    = (const float*)d_in[2];
  const float* w2    = (const float*)d_in[3];
  const float* w3    = (const float*)d_in[4];
  const float* gamma = (const float*)d_in[5];
  const float* beta  = (const float*)d_in[6];
  const float* Wreg  = (const float*)d_in[7];
  const float* breg  = (const float*)d_in[8];
  const float* u0v   = (const float*)d_in[9];
  const float* v0v   = (const float*)d_in[10];
  float* out = (float*)d_out;

  float* ws   = (float*)d_ws;
  float* h1   = ws;                    // 7,872,512
  float* h2   = h1 + 7872512;          // 1,722,368
  float* h3   = h2 + 1722368;          //   346,112
  float* st   = h3 + 346112;           // 384  (3 layers x 64 x 2)
  float* xst  = st + 384;              // 16
  float* traw = xst + 16;              // 192
  float* tfin = traw + 192;            // 192
  _Float16* Wp = (_Float16*)(tfin + 192);  // 3 x 73728 halfs

  k_prep<<<434, 256, 0, stream>>>(w1, w2, w3, Wp, st);   // zero st+xst + W transforms
  k_xstats<<<1024, 256, 0, stream>>>(x, xst);

  k_conv1_mfma<<<32 * 62 * 2, 256, 0, stream>>>(x, w0, Wp, xst, gamma, beta, h1, st);

  k_convpool_mfma<62, 29, 2><<<32 * 29 * 2, 256, 0, stream>>>(
      h1, Wp + 73728, st, gamma, beta, 1, 1.f / 123008.f, h2, st + 128);

  k_convpool_mfma<29, 13, 1><<<32 * 13, 256, 0, stream>>>(
      h2, Wp + 147456, st + 128, gamma, beta, 2, 1.f / 26912.f, h3, st + 256);

  k_theta<<<32, 256, 0, stream>>>(h3, st + 256, gamma, beta, Wreg, breg, traw);
  k_spectral<<<1, 64, 0, stream>>>(traw, u0v, v0v, tfin);
  k_sample<<<2048, 256, 0, stream>>>(x, tfin, out);
}